// Round 10
// baseline (399.193 us; speedup 1.0000x reference)
//
#include <hip/hip_runtime.h>
#include <hip/hip_bf16.h>
#include <math.h>

#define B_   256
#define L_   196
#define ENC_ 2048
#define DEC_ 512
#define HID_ 512

typedef __attribute__((ext_vector_type(8))) short short8v;
typedef __attribute__((ext_vector_type(4))) short short4v;
typedef __attribute__((ext_vector_type(4))) float f32x4;

static __device__ __forceinline__ short f2bf(float x) {
    unsigned u = __float_as_uint(x);
    u += 0x7fffu + ((u >> 16) & 1u);   // round-to-nearest-even
    return (short)(u >> 16);
}

// ---------------------------------------------------------------------------
// Wf (f32 [512,2048]) -> bf16, PLAIN row-major (B is now consumed directly
// from L2 into registers; no LDS staging, no swizzle needed).
// ---------------------------------------------------------------------------
__global__ __launch_bounds__(256) void kconvert(const float* __restrict__ Wf,
                                                short* __restrict__ wfbf) {
    int idx = (blockIdx.x * 256 + threadIdx.x) * 4;   // over 512*2048 = 1M elems
    float4 f = *(const float4*)(Wf + idx);
    short4v h;
    h.x = f2bf(f.x); h.y = f2bf(f.y); h.z = f2bf(f.z); h.w = f2bf(f.w);
    *(short4v*)(wfbf + idx) = h;
}

// ---------------------------------------------------------------------------
// hid_emb[b,h] = hidden[b,:] . Wh[h,:] + bh[h]     (256x512, K=512, fp32)
// ---------------------------------------------------------------------------
__global__ __launch_bounds__(512) void khid(const float* __restrict__ hidden,
                                            const float* __restrict__ Wh,
                                            const float* __restrict__ bh,
                                            float* __restrict__ hid_emb) {
    __shared__ float hs[8][512];
    int t = threadIdx.x;
    int bg = blockIdx.x * 8;
    #pragma unroll
    for (int i = 0; i < 8; ++i) hs[i][t] = hidden[(size_t)(bg + i) * 512 + t];
    __syncthreads();
    float acc[8] = {0.f,0.f,0.f,0.f,0.f,0.f,0.f,0.f};
    const float4* wrow = (const float4*)(Wh + (size_t)t * 512);
    #pragma unroll 4
    for (int d4 = 0; d4 < 128; ++d4) {
        float4 w = wrow[d4];
        int d = d4 * 4;
        #pragma unroll
        for (int i = 0; i < 8; ++i)
            acc[i] += w.x * hs[i][d] + w.y * hs[i][d+1] + w.z * hs[i][d+2] + w.w * hs[i][d+3];
    }
    float bhv = bh[t];
    #pragma unroll
    for (int i = 0; i < 8; ++i)
        hid_emb[(size_t)(bg + i) * 512 + t] = acc[i] + bhv;
}

// ---------------------------------------------------------------------------
// Fused score GEMM v7: 64M x 512N tile, BK=32, 512 threads / 8 waves,
// wave = 64x64 sub-tile.  B BYPASSES LDS: each lane loads its MFMA B-frag
// (16 B) directly from L2-resident wfbf, double-buffered in registers
// (bqA/bqB, prefetch k+1 during MFMA k).  Only A goes through LDS
// (8 KB dbuf, shared by 8 waves), so the per-iter barrier waits lgkmcnt(0)
// ONLY -- all global loads ride across barriers, nothing ever drains vmcnt.
// LDS traffic drops 200 KB -> 36 KB per CU-K-step; bound moves to
// max(MFMA, L2-B) ~= 1300 cy/K-step (vs 3122 measured in v6).
// A-path staging/swizzle/fragment indices are v6-verbatim (verified).
// ---------------------------------------------------------------------------
__global__ __launch_bounds__(512, 4) void kscore(
    const float* __restrict__ feat, const short* __restrict__ wfbf,
    const float* __restrict__ bf, const float* __restrict__ hid_emb,
    const float* __restrict__ We, const float* __restrict__ be,
    float* __restrict__ score)
{
    __shared__ short lds_a[2 * 64 * 32];    // 2 x 4 KB, swizzled [r][k32]
    __shared__ float score_s[8][64];

    const int tid  = threadIdx.x;
    const int wave = tid >> 6;
    const int lane = tid & 63;
    const int g    = lane >> 4;
    const int c    = lane & 15;
    const int m0   = blockIdx.x * 64;

    // ---- A staging geometry (v6-verified) ----
    const int r_a  = tid >> 3;
    const int c4   = tid & 7;
    const float* gA = feat + (size_t)(m0 + r_a) * ENC_ + c4 * 4;
    const int boffA = r_a * 64 + (((c4 >> 1) ^ ((r_a >> 1) & 3)) << 4) + (c4 & 1) * 8;

    // ---- B direct-load base (byte offset into wfbf) ----
    // frag for col n = wave*64 + ni*16 + c : 16 B at [n*ENC + k0 + g*8]
    const char* gB = (const char*)wfbf
                   + ((size_t)(wave * 64 + c) * ENC_ + g * 8) * 2;
    // per-ni offset: ni * 16 * ENC_ * 2 = ni * 65536 bytes
    // per-kt offset: kt * 32 * 2      = kt * 64 bytes

    f32x4 acc[4][4];
    #pragma unroll
    for (int i = 0; i < 4; ++i)
        #pragma unroll
        for (int j = 0; j < 4; ++j)
            acc[i][j] = (f32x4)0.f;

    short8v bqA[4], bqB[4];

#define LOAD_BQ(DST, KT)                                                      \
    _Pragma("unroll")                                                         \
    for (int ni = 0; ni < 4; ++ni)                                            \
        DST[ni] = *(const short8v*)(gB + ni * 65536 + (KT) * 64);

#define COMPUTE(BQ, BUF)                                                      \
    {                                                                         \
        const char* la = (const char*)lds_a + (BUF) * 4096;                   \
        _Pragma("unroll")                                                     \
        for (int mi = 0; mi < 4; ++mi) {                                      \
            int row = mi * 16 + c;                                            \
            int un  = g ^ ((row >> 1) & 3);                                   \
            short8v af = *(const short8v*)(la + row * 64 + un * 16);          \
            _Pragma("unroll")                                                 \
            for (int ni = 0; ni < 4; ++ni)                                    \
                acc[mi][ni] = __builtin_amdgcn_mfma_f32_16x16x32_bf16(        \
                    af, BQ[ni], acc[mi][ni], 0, 0, 0);                        \
        }                                                                     \
    }

#define WRITE_A(FA, BUF)                                                      \
    {                                                                         \
        short4v h0;                                                           \
        h0.x = f2bf((FA).x); h0.y = f2bf((FA).y);                             \
        h0.z = f2bf((FA).z); h0.w = f2bf((FA).w);                             \
        char* wa = (char*)lds_a + (BUF) * 4096;                               \
        *(short4v*)(wa + boffA) = h0;                                         \
    }

    // lgkm-only barrier: LDS ops drained, global loads stay in flight.
#define LBAR                                                                  \
    asm volatile("s_waitcnt lgkmcnt(0)" ::: "memory");                        \
    __builtin_amdgcn_sched_barrier(0);                                        \
    __builtin_amdgcn_s_barrier();                                             \
    __builtin_amdgcn_sched_barrier(0);

#define ITER(KT, CUR, NXT)                                                    \
    {                                                                         \
        const int ka = ((KT) + 2 <= 63) ? (KT) + 2 : 63;   /* clamp */        \
        fa_nxt = *(const float4*)(gA + ka * 32);           /* A(k+2) */       \
        LOAD_BQ(NXT, (KT) + 1)                             /* B(k+1) */       \
        COMPUTE(CUR, (KT) & 1)                                                \
        WRITE_A(fa_cur, ((KT) & 1) ^ 1)                    /* A(k+1) */       \
        fa_cur = fa_nxt;                                                      \
        LBAR                                                                  \
    }

    // ---- prologue: A(0),A(1) global; B(0) -> bqA; write A(0) ----
    float4 fa_cur = *(const float4*)(gA);
    float4 fa_nxt = *(const float4*)(gA + 32);
    LOAD_BQ(bqA, 0)
    WRITE_A(fa_cur, 0)          // compiler auto-waits fa_cur's vmcnt
    fa_cur = fa_nxt;
    LBAR                        // bqA + fa(1) still in flight

    // ---- main loop: kt = 0..61 (pairs), 62 single, 63 peeled compute ----
    for (int kt2 = 0; kt2 < 31; ++kt2) {
        ITER(2 * kt2,     bqA, bqB)
        ITER(2 * kt2 + 1, bqB, bqA)
    }
    ITER(62, bqA, bqB)
    COMPUTE(bqB, 1)             // kt = 63

#undef LOAD_BQ
#undef COMPUTE
#undef WRITE_A
#undef LBAR
#undef ITER

    // ---- fused epilogue: +bf +hid_emb, relu, dot We, reduce over n ----
    float wev[4], bfv[4];
    #pragma unroll
    for (int ni = 0; ni < 4; ++ni) {
        int n = wave * 64 + ni * 16 + c;
        wev[ni] = We[n];
        bfv[ni] = bf[n];
    }
    #pragma unroll
    for (int mi = 0; mi < 4; ++mi) {
        float part[4] = {0.f, 0.f, 0.f, 0.f};
        #pragma unroll
        for (int j = 0; j < 4; ++j) {
            int row  = mi * 16 + g * 4 + j;            // C/D: row=(lane>>4)*4+reg
            int bidx = (m0 + row) / 196;
            const float* hrow = hid_emb + (size_t)bidx * 512;
            #pragma unroll
            for (int ni = 0; ni < 4; ++ni) {
                int n = wave * 64 + ni * 16 + c;
                float v = acc[mi][ni][j] + bfv[ni] + hrow[n];
                v = fmaxf(v, 0.f);
                part[j] += v * wev[ni];
            }
        }
        #pragma unroll
        for (int j = 0; j < 4; ++j) {
            float p = part[j];
            p += __shfl_xor(p, 1, 16);
            p += __shfl_xor(p, 2, 16);
            p += __shfl_xor(p, 4, 16);
            p += __shfl_xor(p, 8, 16);
            if (c == 0) score_s[wave][mi * 16 + g * 4 + j] = p;
        }
    }
    __syncthreads();
    if (tid < 64) {
        float s = be[0];
        #pragma unroll
        for (int w = 0; w < 8; ++w) s += score_s[w][tid];
        score[m0 + tid] = s;
    }
}

// ---------------------------------------------------------------------------
// Softmax over L=196 + output[b,e] = sum_l w[l] * feature[b,l,e].
// ---------------------------------------------------------------------------
__global__ __launch_bounds__(256) void kout(
    const float* __restrict__ score, const float* __restrict__ feat,
    float* __restrict__ out_o, float* __restrict__ out_w)
{
    __shared__ float wbuf[196];
    __shared__ float red[8];
    int t    = threadIdx.x;
    int b    = blockIdx.x >> 1;
    int half = blockIdx.x & 1;
    int w    = t >> 6, lane = t & 63;

    float s = (t < 196) ? score[b * 196 + t] : -1e30f;
    float m = s;
    #pragma unroll
    for (int off = 32; off >= 1; off >>= 1) m = fmaxf(m, __shfl_xor(m, off, 64));
    if (lane == 0) red[w] = m;
    __syncthreads();
    m = fmaxf(fmaxf(red[0], red[1]), fmaxf(red[2], red[3]));
    float e = (t < 196) ? __expf(s - m) : 0.f;
    float sum = e;
    #pragma unroll
    for (int off = 32; off >= 1; off >>= 1) sum += __shfl_xor(sum, off, 64);
    if (lane == 0) red[4 + w] = sum;
    __syncthreads();
    sum = red[4] + red[5] + red[6] + red[7];
    float wt = e / sum;
    if (t < 196) {
        wbuf[t] = wt;
        if (half == 0) out_w[b * 196 + t] = wt;
    }
    __syncthreads();

    int e0 = half * 1024 + t * 4;
    float4 acc = make_float4(0.f, 0.f, 0.f, 0.f);
    const float* fb = feat + (size_t)b * L_ * ENC_ + e0;
    #pragma unroll 4
    for (int l = 0; l < 196; ++l) {
        float4 v = *(const float4*)(fb + (size_t)l * ENC_);
        float wl = wbuf[l];
        acc.x += wl * v.x; acc.y += wl * v.y; acc.z += wl * v.z; acc.w += wl * v.w;
    }
    *(float4*)(out_o + (size_t)b * ENC_ + e0) = acc;
}

extern "C" void kernel_launch(void* const* d_in, const int* in_sizes, int n_in,
                              void* d_out, int out_size, void* d_ws, size_t ws_size,
                              hipStream_t stream) {
    (void)in_sizes; (void)n_in; (void)out_size; (void)ws_size;
    const float* feature = (const float*)d_in[0];
    const float* hidden  = (const float*)d_in[1];
    const float* Wf      = (const float*)d_in[2];
    const float* bf      = (const float*)d_in[3];
    const float* Wh      = (const float*)d_in[4];
    const float* bh      = (const float*)d_in[5];
    const float* We      = (const float*)d_in[6];
    const float* be      = (const float*)d_in[7];

    char* ws = (char*)d_ws;
    short* wfbf    = (short*)ws;                               // 2 MB
    float* hid_emb = (float*)(ws + (2u << 20));                // 512 KB
    float* score   = (float*)(ws + (2u << 20) + (512u << 10)); // 200 KB

    float* out_o = (float*)d_out;                 // [256,2048]
    float* out_w = out_o + (size_t)B_ * ENC_;     // [256,196]

    kconvert<<<dim3(1024), dim3(256), 0, stream>>>(Wf, wfbf);
    khid<<<dim3(32), dim3(512), 0, stream>>>(hidden, Wh, bh, hid_emb);
    kscore<<<dim3(784), dim3(512), 0, stream>>>(feature, wfbf, bf, hid_emb, We, be, score);
    kout<<<dim3(512), dim3(256), 0, stream>>>(score, feature, (float*)d_out, out_w);
}

// Round 11
// 395.794 us; speedup vs baseline: 1.0086x; 1.0086x over previous
//
#include <hip/hip_runtime.h>
#include <hip/hip_bf16.h>
#include <math.h>

#define B_   256
#define L_   196
#define ENC_ 2048
#define DEC_ 512
#define HID_ 512

typedef __attribute__((ext_vector_type(8))) short short8v;
typedef __attribute__((ext_vector_type(4))) short short4v;
typedef __attribute__((ext_vector_type(4))) float f32x4;

static __device__ __forceinline__ short f2bf(float x) {
    unsigned u = __float_as_uint(x);
    u += 0x7fffu + ((u >> 16) & 1u);   // round-to-nearest-even
    return (short)(u >> 16);
}

// ---------------------------------------------------------------------------
// Wf (f32 [512,2048]) -> bf16, PRE-SWIZZLED for BK=32 tiles (v6 layout):
// within each 64B (4-unit) K-tile segment of row n,
// physical unit = logical ^ ((n>>1)&3).   2-way max bank aliasing (free).
// ---------------------------------------------------------------------------
__global__ __launch_bounds__(256) void kconvert(const float* __restrict__ Wf,
                                                short* __restrict__ wfbf) {
    int idx = (blockIdx.x * 256 + threadIdx.x) * 4;   // over 512*2048 = 1M elems
    int n  = idx >> 11;
    int e0 = idx & 2047;
    float4 f = *(const float4*)(Wf + idx);
    short4v h;
    h.x = f2bf(f.x); h.y = f2bf(f.y); h.z = f2bf(f.z); h.w = f2bf(f.w);
    int tile = e0 >> 5;                      // 32-elem K-tile within row
    int lu   = (e0 >> 3) & 3;                // logical 8-elem unit in tile
    int pu   = lu ^ ((n >> 1) & 3);          // physical unit (swizzled)
    int off  = n * 2048 + tile * 32 + pu * 8 + (e0 & 7);
    *(short4v*)(wfbf + off) = h;
}

// ---------------------------------------------------------------------------
// hid_emb[b,h] = hidden[b,:] . Wh[h,:] + bh[h]     (256x512, K=512, fp32)
// ---------------------------------------------------------------------------
__global__ __launch_bounds__(512) void khid(const float* __restrict__ hidden,
                                            const float* __restrict__ Wh,
                                            const float* __restrict__ bh,
                                            float* __restrict__ hid_emb) {
    __shared__ float hs[8][512];
    int t = threadIdx.x;
    int bg = blockIdx.x * 8;
    #pragma unroll
    for (int i = 0; i < 8; ++i) hs[i][t] = hidden[(size_t)(bg + i) * 512 + t];
    __syncthreads();
    float acc[8] = {0.f,0.f,0.f,0.f,0.f,0.f,0.f,0.f};
    const float4* wrow = (const float4*)(Wh + (size_t)t * 512);
    #pragma unroll 4
    for (int d4 = 0; d4 < 128; ++d4) {
        float4 w = wrow[d4];
        int d = d4 * 4;
        #pragma unroll
        for (int i = 0; i < 8; ++i)
            acc[i] += w.x * hs[i][d] + w.y * hs[i][d+1] + w.z * hs[i][d+2] + w.w * hs[i][d+3];
    }
    float bhv = bh[t];
    #pragma unroll
    for (int i = 0; i < 8; ++i)
        hid_emb[(size_t)(bg + i) * 512 + t] = acc[i] + bhv;
}

// ---------------------------------------------------------------------------
// Fused score GEMM v8: 64M x 512N tile, BK=32, 512 threads / 8 waves,
// wave = 64x64 sub-tile.  LOAD-CONCURRENCY schedule:
//   B TRIPLE-buffered LDS: iter k stages B(k+2) -> buf (k+2)%3; the barrier
//     only needs B(k+1) (issued 1.2 iters ago, L2-hot) retired.
//   A ring-4 in registers: iter k issues A(k+4), consumes A(k+1) (3-iter
//     lead); the in-order vmcnt queue never force-retires an A below
//     ~1.8-iter (~1400 cy) lead -> A streams at full HBM rate.
// Steady barrier: s_waitcnt vmcnt(6) lgkmcnt(0)   [leaves A(k+3), B(k+2)x4,
// A(k+4) in flight].  Prologue barrier vmcnt(7).  LDS 106 KB -> 1 block/CU
// (R6 showed occupancy is not binding; concurrency is).
// All index formulas (swizzle, fragments, epilogue) v6-verbatim.
// ---------------------------------------------------------------------------
__global__ __launch_bounds__(512, 2) void kscore(
    const float* __restrict__ feat, const short* __restrict__ wfbf,
    const float* __restrict__ bf, const float* __restrict__ hid_emb,
    const float* __restrict__ We, const float* __restrict__ be,
    float* __restrict__ score)
{
    __shared__ short lds_b[3 * 512 * 32];   // 3 x 32 KB, swizzled [n][k32]
    __shared__ short lds_a[2 * 64 * 32];    // 2 x  4 KB, swizzled [r][k32]
    __shared__ float score_s[8][64];

    const int tid  = threadIdx.x;
    const int wave = tid >> 6;
    const int lane = tid & 63;
    const int g    = lane >> 4;
    const int c    = lane & 15;
    const int m0   = blockIdx.x * 64;

    // ---- per-thread A staging geometry (v6-verified) ----
    const int r_a  = tid >> 3;
    const int c4   = tid & 7;
    const float* gA = feat + (size_t)(m0 + r_a) * ENC_ + c4 * 4;
    const int boffA = r_a * 64 + (((c4 >> 1) ^ ((r_a >> 1) & 3)) << 4) + (c4 & 1) * 8;

    f32x4 acc[4][4];
    #pragma unroll
    for (int i = 0; i < 4; ++i)
        #pragma unroll
        for (int j = 0; j < 4; ++j)
            acc[i][j] = (f32x4)0.f;

#define STAGE_B(K0, BUF)                                                      \
    {                                                                         \
        short* bbase = lds_b + (size_t)(BUF) * 16384;                         \
        _Pragma("unroll")                                                     \
        for (int j = 0; j < 4; ++j) {                                         \
            int ubase = j * 512 + wave * 64;       /* wave-uniform unit base */\
            int ulin  = ubase + lane;              /* 2048 units total      */\
            int n = ulin >> 2, u = ulin & 3;                                  \
            const short* gp = wfbf + (size_t)n * ENC_ + (K0) + u * 8;         \
            short* lp = bbase + (size_t)ubase * 8;                            \
            __builtin_amdgcn_global_load_lds(                                 \
                (const __attribute__((address_space(1))) void*)gp,            \
                (__attribute__((address_space(3))) void*)lp, 16, 0, 0);       \
        }                                                                     \
    }

#define COMPUTE_TILE(ABUF, BBUF)                                              \
    {                                                                         \
        const char* la = (const char*)lds_a + (ABUF) * 4096;                  \
        const char* lb = (const char*)lds_b + (size_t)(BBUF) * 32768;         \
        short8v af[4], bq[4];                                                 \
        _Pragma("unroll")                                                     \
        for (int mi = 0; mi < 4; ++mi) {                                      \
            int row = mi * 16 + c;                                            \
            int un  = g ^ ((row >> 1) & 3);                                   \
            af[mi] = *(const short8v*)(la + row * 64 + un * 16);              \
        }                                                                     \
        _Pragma("unroll")                                                     \
        for (int ni = 0; ni < 4; ++ni) {                                      \
            int n  = wave * 64 + ni * 16 + c;                                 \
            int un = g ^ ((n >> 1) & 3);                                      \
            bq[ni] = *(const short8v*)(lb + n * 64 + un * 16);                \
        }                                                                     \
        _Pragma("unroll")                                                     \
        for (int mi = 0; mi < 4; ++mi)                                        \
            _Pragma("unroll")                                                 \
            for (int ni = 0; ni < 4; ++ni)                                    \
                acc[mi][ni] = __builtin_amdgcn_mfma_f32_16x16x32_bf16(        \
                    af[mi], bq[ni], acc[mi][ni], 0, 0, 0);                    \
    }

#define WRITE_A(FA, BUF)                                                      \
    {                                                                         \
        short4v h0;                                                           \
        h0.x = f2bf((FA).x); h0.y = f2bf((FA).y);                             \
        h0.z = f2bf((FA).z); h0.w = f2bf((FA).w);                             \
        char* wa = (char*)lds_a + (BUF) * 4096;                               \
        *(short4v*)(wa + boffA) = h0;                                         \
    }

#define BAR_COUNTED(N)                                                        \
    asm volatile("s_waitcnt vmcnt(" #N ") lgkmcnt(0)" ::: "memory");          \
    __builtin_amdgcn_sched_barrier(0);                                        \
    __builtin_amdgcn_s_barrier();                                             \
    __builtin_amdgcn_sched_barrier(0);

    // ---- prologue: B(0),B(1) staged; A ring primed with A(1..3) ----
    float4 a0  = *(const float4*)(gA);               // A(0)
    STAGE_B(0, 0)                                    // B(0) [4 vmem]
    STAGE_B(32, 1)                                   // B(1) [4 vmem]
    float4 fa0 = *(const float4*)(gA + 32);          // A(1)
    float4 fa1 = *(const float4*)(gA + 64);          // A(2)
    float4 fa2 = *(const float4*)(gA + 96);          // A(3)
    float4 fa3;
    WRITE_A(a0, 0)                                   // waits a0 only (oldest)
    BAR_COUNTED(7)                                   // retire B(0); 7 in flight

    // ---- main loop: kt = 0..61 ----
    int bc = 0;                                      // compute B-buf = kt%3
    int bs = 2;                                      // stage   B-buf = (kt+2)%3
    for (int kt = 0; kt < 62; ++kt) {
        STAGE_B((kt + 2) * 32, bs)                   // B(k+2) [4 vmem]
        int ka = (kt + 4 > 63) ? 63 : kt + 4;        // clamped (uniform count)
        fa3 = *(const float4*)(gA + ka * 32);        // A(k+4) [1 vmem]
        COMPUTE_TILE(kt & 1, bc)
        WRITE_A(fa0, (kt & 1) ^ 1)                   // A(k+1): 3-iter lead
        fa0 = fa1; fa1 = fa2; fa2 = fa3;
        BAR_COUNTED(6)                               // retire B(k+1) only
        bc = (bc == 2) ? 0 : bc + 1;
        bs = (bs == 2) ? 0 : bs + 1;
    }
    // ---- peel kt = 62 ----
    COMPUTE_TILE(0, 2)                               // 62&1=0, 62%3=2
    WRITE_A(fa0, 1)                                  // A(63)
    BAR_COUNTED(0)
    // ---- peel kt = 63 ----
    COMPUTE_TILE(1, 0)                               // 63&1=1, 63%3=0

#undef STAGE_B
#undef COMPUTE_TILE
#undef WRITE_A
#undef BAR_COUNTED

    // ---- fused epilogue: +bf +hid_emb, relu, dot We, reduce over n ----
    float wev[4], bfv[4];
    #pragma unroll
    for (int ni = 0; ni < 4; ++ni) {
        int n = wave * 64 + ni * 16 + c;
        wev[ni] = We[n];
        bfv[ni] = bf[n];
    }
    #pragma unroll
    for (int mi = 0; mi < 4; ++mi) {
        float part[4] = {0.f, 0.f, 0.f, 0.f};
        #pragma unroll
        for (int j = 0; j < 4; ++j) {
            int row  = mi * 16 + g * 4 + j;            // C/D: row=(lane>>4)*4+reg
            int bidx = (m0 + row) / 196;
            const float* hrow = hid_emb + (size_t)bidx * 512;
            #pragma unroll
            for (int ni = 0; ni < 4; ++ni) {
                int n = wave * 64 + ni * 16 + c;
                float v = acc[mi][ni][j] + bfv[ni] + hrow[n];
                v = fmaxf(v, 0.f);
                part[j] += v * wev[ni];
            }
        }
        #pragma unroll
        for (int j = 0; j < 4; ++j) {
            float p = part[j];
            p += __shfl_xor(p, 1, 16);
            p += __shfl_xor(p, 2, 16);
            p += __shfl_xor(p, 4, 16);
            p += __shfl_xor(p, 8, 16);
            if (c == 0) score_s[wave][mi * 16 + g * 4 + j] = p;
        }
    }
    __syncthreads();
    if (tid < 64) {
        float s = be[0];
        #pragma unroll
        for (int w = 0; w < 8; ++w) s += score_s[w][tid];
        score[m0 + tid] = s;
    }
}

// ---------------------------------------------------------------------------
// Softmax over L=196 + output[b,e] = sum_l w[l] * feature[b,l,e].
// ---------------------------------------------------------------------------
__global__ __launch_bounds__(256) void kout(
    const float* __restrict__ score, const float* __restrict__ feat,
    float* __restrict__ out_o, float* __restrict__ out_w)
{
    __shared__ float wbuf[196];
    __shared__ float red[8];
    int t    = threadIdx.x;
    int b    = blockIdx.x >> 1;
    int half = blockIdx.x & 1;
    int w    = t >> 6, lane = t & 63;

    float s = (t < 196) ? score[b * 196 + t] : -1e30f;
    float m = s;
    #pragma unroll
    for (int off = 32; off >= 1; off >>= 1) m = fmaxf(m, __shfl_xor(m, off, 64));
    if (lane == 0) red[w] = m;
    __syncthreads();
    m = fmaxf(fmaxf(red[0], red[1]), fmaxf(red[2], red[3]));
    float e = (t < 196) ? __expf(s - m) : 0.f;
    float sum = e;
    #pragma unroll
    for (int off = 32; off >= 1; off >>= 1) sum += __shfl_xor(sum, off, 64);
    if (lane == 0) red[4 + w] = sum;
    __syncthreads();
    sum = red[4] + red[5] + red[6] + red[7];
    float wt = e / sum;
    if (t < 196) {
        wbuf[t] = wt;
        if (half == 0) out_w[b * 196 + t] = wt;
    }
    __syncthreads();

    int e0 = half * 1024 + t * 4;
    float4 acc = make_float4(0.f, 0.f, 0.f, 0.f);
    const float* fb = feat + (size_t)b * L_ * ENC_ + e0;
    #pragma unroll 4
    for (int l = 0; l < 196; ++l) {
        float4 v = *(const float4*)(fb + (size_t)l * ENC_);
        float wl = wbuf[l];
        acc.x += wl * v.x; acc.y += wl * v.y; acc.z += wl * v.z; acc.w += wl * v.w;
    }
    *(float4*)(out_o + (size_t)b * ENC_ + e0) = acc;
}

extern "C" void kernel_launch(void* const* d_in, const int* in_sizes, int n_in,
                              void* d_out, int out_size, void* d_ws, size_t ws_size,
                              hipStream_t stream) {
    (void)in_sizes; (void)n_in; (void)out_size; (void)ws_size;
    const float* feature = (const float*)d_in[0];
    const float* hidden  = (const float*)d_in[1];
    const float* Wf      = (const float*)d_in[2];
    const float* bf      = (const float*)d_in[3];
    const float* Wh      = (const float*)d_in[4];
    const float* bh      = (const float*)d_in[5];
    const float* We      = (const float*)d_in[6];
    const float* be      = (const float*)d_in[7];

    char* ws = (char*)d_ws;
    short* wfbf    = (short*)ws;                               // 2 MB
    float* hid_emb = (float*)(ws + (2u << 20));                // 512 KB
    float* score   = (float*)(ws + (2u << 20) + (512u << 10)); // 200 KB

    float* out_o = (float*)d_out;                 // [256,2048]
    float* out_w = out_o + (size_t)B_ * ENC_;     // [256,196]

    kconvert<<<dim3(1024), dim3(256), 0, stream>>>(Wf, wfbf);
    khid<<<dim3(32), dim3(512), 0, stream>>>(hidden, Wh, bh, hid_emb);
    kscore<<<dim3(784), dim3(512), 0, stream>>>(feature, wfbf, bf, hid_emb, We, be, score);
    kout<<<dim3(512), dim3(256), 0, stream>>>(score, feature, (float*)d_out, out_w);
}